// Round 7
// baseline (332.297 us; speedup 1.0000x reference)
//
#include <hip/hip_runtime.h>

// CSM_62216896250023: emb gather (16384,7,1024) -> 4 stacked depthwise seq-convs
// with sigmoid, seq 7->6->5->3->1, out (16384,1024) f32.
//
// R8: TLP experiment, zero inline asm. R6/R6b/R7 all failed on the same
// structural hazard: invisible-asm load results carried through compiler-
// allocated SSA can be copied (v_mov) BEFORE the hand-counted wait -> stale
// data. "+v" ownership waits tie in=out but NOT to the load's register ->
// unverifiable. Dropped entirely. R5 also showed intra-wave pipelining is
// worth only ~4% (97 vs 101us) -> not the valuable part. What remains
// untested is concurrency: R5 ran 16 waves/CU at 35% occupancy, 39% VALU,
// no BW ceiling (logical 4.85 TB/s, HBM 3.0, L2 2.5), ~25K cyc wait per 7KB
// row => queue-limited and under-subscribed.
//  - 512-thread blocks, 16 rows (two 8-row halves by tid>>8) sharing the
//    40KB LDS weights -> 4 blocks/CU = 32 waves/CU (2x R5).
//  - fully compiler-visible gathers: compiler emits its own waitcnt ->
//    correctness by construction; per-row load->compute->store, latency
//    hidden by TLP (8 waves/SIMD round-robin).
//  - p-outer compute (R5's low-pressure form) + b128 LDS taps (R5's b64
//    taps cost 5.2M bank-conflict cycles; b128 measured 0 in R4b).
//  - __launch_bounds__(512,8): 64-VGPR target for 8 waves/SIMD. Health
//    check: WRITE_SIZE == 65536 exactly (any spill shows up here).
//  - __builtin_nontemporal_store on native ext-vector f4 (R4b-proven).
// Fork on result: dur -> 55-70us => concurrency was the limit. dur flat at
// ~95us with occupancy ~2x => per-CU miss-handling saturated -> attack bytes.

constexpr int EMBED = 1024;
constexpr int SEQ   = 7;
constexpr int ROWSB = 16;   // batch rows per block
constexpr int ROWS  = 8;    // rows per half-block wave set
constexpr int TAPS  = 10;   // c1(2) + c2(2) + c3(3) + c4(3)

typedef float f2 __attribute__((ext_vector_type(2)));
typedef float f4 __attribute__((ext_vector_type(4)));

__device__ __forceinline__ f2 sig2(f2 y) {
    // y = -log2(e) * preact (scale folded into weights);  sigmoid = 1/(1 + 2^y)
    f2 u;
    u.x = __builtin_amdgcn_exp2f(y.x);
    u.y = __builtin_amdgcn_exp2f(y.y);
    f2 d = u + (f2){1.0f, 1.0f};
    f2 r;
    r.x = __builtin_amdgcn_rcpf(d.x);
    r.y = __builtin_amdgcn_rcpf(d.y);
    return r;
}

__device__ __forceinline__ f2 vhalf(f4 f, int p) {
    return p ? (f2){f.z, f.w} : (f2){f.x, f.y};
}

__device__ __forceinline__ f4 ldw128(const float* wl, int tap, int e) {
    return *(const f4*)(wl + tap * EMBED + e);        // ds_read_b128
}

// p-outer: halves live temporaries vs joint-lane form (R5-measured 52 VGPR).
__device__ __forceinline__ f4 compute_row(const f4 v[SEQ], const float* wl, int e) {
    f2 o[2];
#pragma unroll
    for (int p = 0; p < 2; ++p) {
        f4 wA = ldw128(wl, 0, e), wB = ldw128(wl, 1, e), wC;
        f2 h1[6];
#pragma unroll
        for (int l = 0; l < 6; ++l)
            h1[l] = sig2(vhalf(v[l], p) * vhalf(wA, p)
                         + vhalf(v[l + 1], p) * vhalf(wB, p));
        wA = ldw128(wl, 2, e); wB = ldw128(wl, 3, e);
        f2 h2[5];
#pragma unroll
        for (int l = 0; l < 5; ++l)
            h2[l] = sig2(h1[l] * vhalf(wA, p) + h1[l + 1] * vhalf(wB, p));
        wA = ldw128(wl, 4, e); wB = ldw128(wl, 5, e); wC = ldw128(wl, 6, e);
        f2 h3[3];
#pragma unroll
        for (int l = 0; l < 3; ++l)
            h3[l] = sig2(h2[l] * vhalf(wA, p) + h2[l + 1] * vhalf(wB, p)
                         + h2[l + 2] * vhalf(wC, p));
        wA = ldw128(wl, 7, e); wB = ldw128(wl, 8, e); wC = ldw128(wl, 9, e);
        o[p] = sig2(h3[0] * vhalf(wA, p) + h3[1] * vhalf(wB, p)
                    + h3[2] * vhalf(wC, p));
    }
    f4 of;
    of.x = o[0].x; of.y = o[0].y; of.z = o[1].x; of.w = o[1].y;
    return of;
}

__global__ __launch_bounds__(512, 8) void CSM_62216896250023_kernel(
    const int*   __restrict__ X,
    const float* __restrict__ emb,
    const float* __restrict__ c1,
    const float* __restrict__ c2,
    const float* __restrict__ c3,
    const float* __restrict__ c4,
    float*       __restrict__ out)
{
    __shared__ float wlds[TAPS * EMBED];

    const int tid  = threadIdx.x;
    const int e    = (tid & 255) << 2;          // float index within embed row
    // Half-block row base: wave-uniform (tid>>8 constant within a wave);
    // readfirstlane legitimizes SGPR residency -> idx loads go via SMEM.
    const int b0 = __builtin_amdgcn_readfirstlane(
        blockIdx.x * ROWSB + (tid >> 8) * ROWS);

    // ---- stage prescaled weights into LDS (waves 0-3 only; uniform branch) ----
    const float NL2E = -1.44269504088896f;
    if (tid < 256) {
        const float* src[TAPS] = {c1, c1 + EMBED,
                                  c2, c2 + EMBED,
                                  c3, c3 + EMBED, c3 + 2 * EMBED,
                                  c4, c4 + EMBED, c4 + 2 * EMBED};
#pragma unroll
        for (int t = 0; t < TAPS; ++t) {          // t compile-time: src[t] folds
            f4 f = *(const f4*)(src[t] + e);
            f *= NL2E;
            *(f4*)&wlds[t * EMBED + e] = f;
        }
    }

    // ---- indices: uniform (SGPR) address -> SMEM loads ----
    int idx[ROWS][SEQ];
#pragma unroll
    for (int r = 0; r < ROWS; ++r)
#pragma unroll
        for (int t = 0; t < SEQ; ++t)
            idx[r][t] = X[(b0 + r) * SEQ + t];

    __syncthreads();

    // ---- per-row load -> compute -> store; latency hidden by 8 waves/SIMD ----
#pragma unroll
    for (int r = 0; r < ROWS; ++r) {
        f4 v[SEQ];
#pragma unroll
        for (int t = 0; t < SEQ; ++t)
            v[t] = *(const f4*)(emb + (size_t)(unsigned)idx[r][t] * EMBED + e);

        f4 o = compute_row(v, wlds, e);
        __builtin_nontemporal_store(o, (f4*)(out + (size_t)(b0 + r) * EMBED + e));
    }
}

extern "C" void kernel_launch(void* const* d_in, const int* in_sizes, int n_in,
                              void* d_out, int out_size, void* d_ws, size_t ws_size,
                              hipStream_t stream) {
    const int*   X   = (const int*)d_in[0];
    const float* emb = (const float*)d_in[1];
    const float* c1  = (const float*)d_in[2];
    const float* c2  = (const float*)d_in[3];
    const float* c3  = (const float*)d_in[4];
    const float* c4  = (const float*)d_in[5];
    float* out = (float*)d_out;

    const int batch = in_sizes[0] / SEQ;        // 16384
    CSM_62216896250023_kernel<<<batch / ROWSB, 512, 0, stream>>>(X, emb, c1, c2, c3, c4, out);
}

// Round 8
// 249.142 us; speedup vs baseline: 1.3338x; 1.3338x over previous
//
#include <hip/hip_runtime.h>

// CSM_62216896250023: emb gather (16384,7,1024) -> 4 stacked depthwise seq-convs
// with sigmoid, seq 7->6->5->3->1, out (16384,1024) f32.
//
// R9: R8 minus the launch_bounds occupancy floor. Session ledger: EVERY
// kernel with a min-occupancy floor spilled or collapsed (R3 (256,4)->44reg
// serialized; R4b (256,4)->spill; R8 (512,8)->VGPR=32 + 212MB scratch writes,
// 185us); every kernel without one allocated cleanly (R5: 52 VGPR, 0 spill).
// Rule: never pass the second arg here.
// R8's useful datum: at 72% occupancy the memory system sustained 3.79 TB/s
// (R5: 3.06 at 35%) -> delivered BW scales with resident waves; the
// under-subscription theory holds but has never run unpolluted by spills.
// R9 is that clean experiment:
//  - 512-thread blocks, 16 rows (two 8-row halves by tid>>8) sharing the
//    40KB LDS weights -> LDS caps 4 blocks/CU = 32 waves/CU (2x R5).
//  - natural VGPR allocation (~52 demand) -> 8 waves/SIMD fits at <=64.
//  - fully compiler-visible gathers (compiler-correct waitcnt; the asm
//    pipeline line R5-R7 is dead: invisible loads + allocator copies are
//    unverifiable, and R5 proved intra-wave pipelining worth only ~4%).
//  - p-outer compute + b128 LDS taps (0 bank conflicts, confirmed R8).
//  - nontemporal f4 stores (write-once stream, keep L2/L3 for emb).
// Fork: dur ~60-75us => concurrency was the limiter. dur flat ~90-100us at
// ~2x occupancy => per-CU gather issue/service limit -> next round halves
// bytes (bf16 emb staging pass), not concurrency.

constexpr int EMBED = 1024;
constexpr int SEQ   = 7;
constexpr int ROWSB = 16;   // batch rows per block
constexpr int ROWS  = 8;    // rows per half-block wave set
constexpr int TAPS  = 10;   // c1(2) + c2(2) + c3(3) + c4(3)

typedef float f2 __attribute__((ext_vector_type(2)));
typedef float f4 __attribute__((ext_vector_type(4)));

__device__ __forceinline__ f2 sig2(f2 y) {
    // y = -log2(e) * preact (scale folded into weights);  sigmoid = 1/(1 + 2^y)
    f2 u;
    u.x = __builtin_amdgcn_exp2f(y.x);
    u.y = __builtin_amdgcn_exp2f(y.y);
    f2 d = u + (f2){1.0f, 1.0f};
    f2 r;
    r.x = __builtin_amdgcn_rcpf(d.x);
    r.y = __builtin_amdgcn_rcpf(d.y);
    return r;
}

__device__ __forceinline__ f2 vhalf(f4 f, int p) {
    return p ? (f2){f.z, f.w} : (f2){f.x, f.y};
}

__device__ __forceinline__ f4 ldw128(const float* wl, int tap, int e) {
    return *(const f4*)(wl + tap * EMBED + e);        // ds_read_b128
}

// p-outer: halves live temporaries vs joint-lane form (R5-measured 52 VGPR).
__device__ __forceinline__ f4 compute_row(const f4 v[SEQ], const float* wl, int e) {
    f2 o[2];
#pragma unroll
    for (int p = 0; p < 2; ++p) {
        f4 wA = ldw128(wl, 0, e), wB = ldw128(wl, 1, e), wC;
        f2 h1[6];
#pragma unroll
        for (int l = 0; l < 6; ++l)
            h1[l] = sig2(vhalf(v[l], p) * vhalf(wA, p)
                         + vhalf(v[l + 1], p) * vhalf(wB, p));
        wA = ldw128(wl, 2, e); wB = ldw128(wl, 3, e);
        f2 h2[5];
#pragma unroll
        for (int l = 0; l < 5; ++l)
            h2[l] = sig2(h1[l] * vhalf(wA, p) + h1[l + 1] * vhalf(wB, p));
        wA = ldw128(wl, 4, e); wB = ldw128(wl, 5, e); wC = ldw128(wl, 6, e);
        f2 h3[3];
#pragma unroll
        for (int l = 0; l < 3; ++l)
            h3[l] = sig2(h2[l] * vhalf(wA, p) + h2[l + 1] * vhalf(wB, p)
                         + h2[l + 2] * vhalf(wC, p));
        wA = ldw128(wl, 7, e); wB = ldw128(wl, 8, e); wC = ldw128(wl, 9, e);
        o[p] = sig2(h3[0] * vhalf(wA, p) + h3[1] * vhalf(wB, p)
                    + h3[2] * vhalf(wC, p));
    }
    f4 of;
    of.x = o[0].x; of.y = o[0].y; of.z = o[1].x; of.w = o[1].y;
    return of;
}

__global__ __launch_bounds__(512) void CSM_62216896250023_kernel(
    const int*   __restrict__ X,
    const float* __restrict__ emb,
    const float* __restrict__ c1,
    const float* __restrict__ c2,
    const float* __restrict__ c3,
    const float* __restrict__ c4,
    float*       __restrict__ out)
{
    __shared__ float wlds[TAPS * EMBED];

    const int tid  = threadIdx.x;
    const int e    = (tid & 255) << 2;          // float index within embed row
    // Half-block row base: wave-uniform (tid>>8 constant within a wave);
    // readfirstlane legitimizes SGPR residency -> idx loads go via SMEM.
    const int b0 = __builtin_amdgcn_readfirstlane(
        blockIdx.x * ROWSB + (tid >> 8) * ROWS);

    // ---- stage prescaled weights into LDS (waves 0-3 only; uniform branch) ----
    const float NL2E = -1.44269504088896f;
    if (tid < 256) {
        const float* src[TAPS] = {c1, c1 + EMBED,
                                  c2, c2 + EMBED,
                                  c3, c3 + EMBED, c3 + 2 * EMBED,
                                  c4, c4 + EMBED, c4 + 2 * EMBED};
#pragma unroll
        for (int t = 0; t < TAPS; ++t) {          // t compile-time: src[t] folds
            f4 f = *(const f4*)(src[t] + e);
            f *= NL2E;
            *(f4*)&wlds[t * EMBED + e] = f;
        }
    }

    // ---- indices: uniform (SGPR) address -> SMEM loads ----
    int idx[ROWS][SEQ];
#pragma unroll
    for (int r = 0; r < ROWS; ++r)
#pragma unroll
        for (int t = 0; t < SEQ; ++t)
            idx[r][t] = X[(b0 + r) * SEQ + t];

    __syncthreads();

    // ---- per-row load -> compute -> store; latency hidden by TLP ----
#pragma unroll
    for (int r = 0; r < ROWS; ++r) {
        f4 v[SEQ];
#pragma unroll
        for (int t = 0; t < SEQ; ++t)
            v[t] = *(const f4*)(emb + (size_t)(unsigned)idx[r][t] * EMBED + e);

        f4 o = compute_row(v, wlds, e);
        __builtin_nontemporal_store(o, (f4*)(out + (size_t)(b0 + r) * EMBED + e));
    }
}

extern "C" void kernel_launch(void* const* d_in, const int* in_sizes, int n_in,
                              void* d_out, int out_size, void* d_ws, size_t ws_size,
                              hipStream_t stream) {
    const int*   X   = (const int*)d_in[0];
    const float* emb = (const float*)d_in[1];
    const float* c1  = (const float*)d_in[2];
    const float* c2  = (const float*)d_in[3];
    const float* c3  = (const float*)d_in[4];
    const float* c4  = (const float*)d_in[5];
    float* out = (float*)d_out;

    const int batch = in_sizes[0] / SEQ;        // 16384
    CSM_62216896250023_kernel<<<batch / ROWSB, 512, 0, stream>>>(X, emb, c1, c2, c3, c4, out);
}